// Round 18
// baseline (239.152 us; speedup 1.0000x reference)
//
#include <hip/hip_runtime.h>
#include <hip/hip_bf16.h>
#include <cstdint>
#include <cstddef>

typedef unsigned short u16;
typedef __bf16 bf16x8 __attribute__((ext_vector_type(8)));
typedef float f32x4 __attribute__((ext_vector_type(4)));

#define LOG2E 1.44269504088896340736f

// packed f32x2 -> bf16x2 (RTNE) in ONE VALU inst; low16=lo, high16=hi
__device__ __forceinline__ uint32_t f2bf2(float lo, float hi) {
  uint32_t r;
  asm("v_cvt_pk_bf16_f32 %0, %1, %2" : "=v"(r) : "v"(lo), "v"(hi));
  return r;
}
__device__ __forceinline__ u16 f2bf(float f) { return (u16)f2bf2(f, f); }

__device__ __forceinline__ void gload16(const u16* g, u16* l) {
  __builtin_amdgcn_global_load_lds(
      (const __attribute__((address_space(1))) void*)g,
      (__attribute__((address_space(3))) void*)l, 16, 0, 0);
}

// XCD-chunked block swizzle (kept from R15; ~neutral but not harmful)
__device__ __forceinline__ void xcd_swizzle(int& bx, int& by) {
  const int gx = gridDim.x;
  const int nwg = gx * gridDim.y;
  const int bid = blockIdx.y * gx + blockIdx.x;
  const int s = (bid & 7) * (nwg >> 3) + (bid >> 3);
  bx = s % gx;
  by = s / gx;
}

// ---- fp32 (1024 x ld) column-stripe -> bf16 transposed slice ----
__global__ __launch_bounds__(256) void transpose_bf16_kernel(
    const float* __restrict__ src, u16* __restrict__ dst, int ld, int c0) {
  __shared__ u16 tile[64][65];
  const int r0 = blockIdx.x * 64, cl0 = blockIdx.y * 64;
  const int tid = threadIdx.x;
#pragma unroll
  for (int i = 0; i < 16; ++i) {
    int idx = i * 256 + tid;
    int r = idx >> 6, c = idx & 63;
    tile[c][r] = f2bf(src[(size_t)(r0 + r) * ld + c0 + cl0 + c]);
  }
  __syncthreads();
#pragma unroll
  for (int i = 0; i < 16; ++i) {
    int idx = i * 256 + tid;
    int c = idx >> 6, r = idx & 63;
    dst[(size_t)(cl0 + c) * 1024 + r0 + r] = tile[c][r];
  }
}

// ---- 3 weight transposes in one launch ----
__global__ __launch_bounds__(256) void prep3_kernel(
    const float* __restrict__ Wa, const float* __restrict__ Wg,
    const float* __restrict__ Wf,
    u16* __restrict__ dv, u16* __restrict__ dg, u16* __restrict__ df) {
  __shared__ u16 tile[64][65];
  const int z = blockIdx.z;
  const float* src = (z == 0) ? Wa : (z == 1) ? Wg : Wf;
  u16* dst = (z == 0) ? dv : (z == 1) ? dg : df;
  const int ld = (z == 0) ? 3072 : 1024;
  const int c0 = (z == 0) ? 2048 : 0;
  const int r0 = blockIdx.x * 64, cl0 = blockIdx.y * 64;
  const int tid = threadIdx.x;
#pragma unroll
  for (int i = 0; i < 16; ++i) {
    int idx = i * 256 + tid;
    int r = idx >> 6, c = idx & 63;
    tile[c][r] = f2bf(src[(size_t)(r0 + r) * ld + c0 + cl0 + c]);
  }
  __syncthreads();
#pragma unroll
  for (int i = 0; i < 16; ++i) {
    int idx = i * 256 + tid;
    int c = idx >> 6, r = idx & 63;
    dst[(size_t)(cl0 + c) * 1024 + r0 + r] = tile[c][r];
  }
}

// ---- GEMM 64x128 tile, A = f32 (reg-staged + bf16 convert), Bt bf16 ----
// EPI 0: N=2048: col<1024 -> O0 (+bias, *scale*log2e); col>=1024 -> O1 (+bias)
// EPI 1: N=1024: O0 bf16, +bias; rows GLOBAL 0..4095, batch stride 4194304 u16
template <int EPI>
__global__ __launch_bounds__(256) void gemm_hA(
    const float* __restrict__ A,
    const u16* __restrict__ Bt,
    u16* __restrict__ O0, u16* __restrict__ O1,
    const float* __restrict__ bias,
    const int* __restrict__ layer_idx) {
  __shared__ u16 lds_a[2][64 * 40];
  __shared__ u16 lds_b[2][128 * 32];
  const int tid = threadIdx.x;
  const int wid = tid >> 6, lane = tid & 63;
  const int lrow = lane & 15, lgrp = lane >> 4;
  int bxs, bys;
  xcd_swizzle(bxs, bys);
  const int brow = bys * 64;
  const int bcol = bxs * 128;
  const int wr = wid >> 1, wc = wid & 1;

  f32x4 acc[2][4] = {};

  const int wchunk0 = wid, wchunk1 = 4 + wid;
  const int cB0 = wchunk0 * 64 + lane, cB1 = wchunk1 * 64 + lane;
  const int rB0 = cB0 >> 2, col8B0 = (cB0 & 3) << 3;
  const int rB1 = cB1 >> 2, col8B1 = (cB1 & 3) << 3;

  // prologue
  gload16(Bt + (size_t)(bcol + rB0) * 1024 + col8B0, lds_b[0] + wchunk0 * 512);
  gload16(Bt + (size_t)(bcol + rB1) * 1024 + col8B1, lds_b[0] + wchunk1 * 512);
  {
    float4 v[2];
#pragma unroll
    for (int j = 0; j < 2; ++j) {
      int idx = j * 256 + tid;
      int m = idx >> 3, k4 = (idx & 7) << 2;
      v[j] = *(const float4*)(A + (size_t)(brow + m) * 1024 + k4);
    }
#pragma unroll
    for (int j = 0; j < 2; ++j) {
      int idx = j * 256 + tid;
      int m = idx >> 3, k4 = (idx & 7) << 2;
      uint2 w;
      w.x = f2bf2(v[j].x, v[j].y);
      w.y = f2bf2(v[j].z, v[j].w);
      *(uint2*)(lds_a[0] + m * 40 + k4) = w;
    }
  }

  for (int k0 = 0; k0 < 1024; k0 += 32) {
    const int bi = (k0 >> 5) & 1;
    __syncthreads();
    bf16x8 af[2], bfr[4];
#pragma unroll
    for (int mi = 0; mi < 2; ++mi)
      af[mi] = *(const bf16x8*)(lds_a[bi] + (wr * 32 + mi * 16 + lrow) * 40 + lgrp * 8);
#pragma unroll
    for (int nj = 0; nj < 4; ++nj)
      bfr[nj] = *(const bf16x8*)(lds_b[bi] + (wc * 64 + nj * 16 + lrow) * 32 + lgrp * 8);

    float4 v[2];
    if (k0 < 992) {
      const int kn = k0 + 32;
      gload16(Bt + (size_t)(bcol + rB0) * 1024 + kn + col8B0, lds_b[bi ^ 1] + wchunk0 * 512);
      gload16(Bt + (size_t)(bcol + rB1) * 1024 + kn + col8B1, lds_b[bi ^ 1] + wchunk1 * 512);
#pragma unroll
      for (int j = 0; j < 2; ++j) {
        int idx = j * 256 + tid;
        int m = idx >> 3, k4 = (idx & 7) << 2;
        v[j] = *(const float4*)(A + (size_t)(brow + m) * 1024 + kn + k4);
      }
    }

#pragma unroll
    for (int mi = 0; mi < 2; ++mi)
#pragma unroll
      for (int nj = 0; nj < 4; ++nj)
        acc[mi][nj] = __builtin_amdgcn_mfma_f32_16x16x32_bf16(af[mi], bfr[nj], acc[mi][nj], 0, 0, 0);

    if (k0 < 992) {
#pragma unroll
      for (int j = 0; j < 2; ++j) {
        int idx = j * 256 + tid;
        int m = idx >> 3, k4 = (idx & 7) << 2;
        uint2 w;
        w.x = f2bf2(v[j].x, v[j].y);
        w.y = f2bf2(v[j].z, v[j].w);
        *(uint2*)(lds_a[bi ^ 1] + m * 40 + k4) = w;
      }
    }
  }

  float scale = 1.0f;
  if (EPI == 0) scale = 0.125f * LOG2E / (1.0f + (float)(*layer_idx));

#pragma unroll
  for (int mi = 0; mi < 2; ++mi) {
#pragma unroll
    for (int nj = 0; nj < 4; ++nj) {
#pragma unroll
      for (int r = 0; r < 4; ++r) {
        int row = brow + wr * 32 + mi * 16 + lgrp * 4 + r;
        int col = bcol + wc * 64 + nj * 16 + lrow;
        float vv = acc[mi][nj][r] + bias[col];
        if (EPI == 0) {
          if (col < 1024) {
            O0[(size_t)row * 1024 + col] = f2bf(vv * scale);
          } else {
            O1[(size_t)row * 1024 + (col - 1024)] = f2bf(vv);
          }
        } else {
          size_t oidx = (size_t)(row >> 11) * 4194304 + (size_t)(row & 2047) * 1024 + col;
          O0[oidx] = f2bf(vv);
        }
      }
    }
  }
}

// ---- fused gate/ff GEMM, 64x128 tile, both batches ----
// Writes VgT with key positions PERMUTED within each 32-key group so that
// attention's PV B-operand slot s holds key pi(s):
//   pi(s): j=s&7, g=s>>3; j<4 -> key g*4+j ; j>=4 -> key 16+g*4+(j-4)
__global__ __launch_bounds__(256) void gemm_gate(
    const u16* __restrict__ A,
    const u16* __restrict__ Bg, const u16* __restrict__ Bf,
    u16* __restrict__ VgT) {
  __shared__ u16 lds_a[2][64 * 32];
  __shared__ u16 lds_g[2][128 * 32];
  __shared__ u16 lds_f[2][128 * 32];
  const int tid = threadIdx.x;
  const int wid = tid >> 6, lane = tid & 63;
  const int lrow = lane & 15, lgrp = lane >> 4;
  int bxs, bys;
  xcd_swizzle(bxs, bys);
  const int browg = bys * 64;
  const int batch = browg >> 11;
  const int brow = browg & 2047;
  const u16* Ab = A + (size_t)batch * 4194304;
  u16* VgTb = VgT + (size_t)batch * 4194304;
  const int bcol = bxs * 128;
  const int wr = wid >> 1, wc = wid & 1;

  f32x4 accg[2][4] = {};
  f32x4 accf[2][4] = {};

  const int wchunk0 = wid, wchunk1 = 4 + wid;
  const int cA = wchunk0 * 64 + lane;
  const int rA = cA >> 2, col8A = (cA & 3) << 3;
  const int cB0 = wchunk0 * 64 + lane, cB1 = wchunk1 * 64 + lane;
  const int rB0 = cB0 >> 2, col8B0 = (cB0 & 3) << 3;
  const int rB1 = cB1 >> 2, col8B1 = (cB1 & 3) << 3;

  auto stage = [&](int k0, int bi) {
    gload16(Ab + (size_t)(brow + rA) * 1024 + k0 + col8A, lds_a[bi] + wchunk0 * 512);
    gload16(Bg + (size_t)(bcol + rB0) * 1024 + k0 + col8B0, lds_g[bi] + wchunk0 * 512);
    gload16(Bg + (size_t)(bcol + rB1) * 1024 + k0 + col8B1, lds_g[bi] + wchunk1 * 512);
    gload16(Bf + (size_t)(bcol + rB0) * 1024 + k0 + col8B0, lds_f[bi] + wchunk0 * 512);
    gload16(Bf + (size_t)(bcol + rB1) * 1024 + k0 + col8B1, lds_f[bi] + wchunk1 * 512);
  };

  stage(0, 0);
  for (int k0 = 0; k0 < 1024; k0 += 32) {
    const int bi = (k0 >> 5) & 1;
    __syncthreads();
    bf16x8 af[2], bg[4], bff[4];
#pragma unroll
    for (int mi = 0; mi < 2; ++mi)
      af[mi] = *(const bf16x8*)(lds_a[bi] + (wr * 32 + mi * 16 + lrow) * 32 + lgrp * 8);
#pragma unroll
    for (int nj = 0; nj < 4; ++nj) {
      bg[nj]  = *(const bf16x8*)(lds_g[bi] + (wc * 64 + nj * 16 + lrow) * 32 + lgrp * 8);
      bff[nj] = *(const bf16x8*)(lds_f[bi] + (wc * 64 + nj * 16 + lrow) * 32 + lgrp * 8);
    }
    if (k0 < 992) stage(k0 + 32, bi ^ 1);
#pragma unroll
    for (int mi = 0; mi < 2; ++mi)
#pragma unroll
      for (int nj = 0; nj < 4; ++nj) {
        accg[mi][nj] = __builtin_amdgcn_mfma_f32_16x16x32_bf16(af[mi], bg[nj],  accg[mi][nj], 0, 0, 0);
        accf[mi][nj] = __builtin_amdgcn_mfma_f32_16x16x32_bf16(af[mi], bff[nj], accf[mi][nj], 0, 0, 0);
      }
  }

#pragma unroll
  for (int mi = 0; mi < 2; ++mi) {
#pragma unroll
    for (int nj = 0; nj < 4; ++nj) {
      int row0 = brow + wr * 32 + mi * 16 + lgrp * 4;  // key position, mult of 4
      int n = bcol + wc * 64 + nj * 16 + lrow;
      int k5 = row0 & 31;
      int s0 = (k5 < 16) ? ((k5 >> 2) * 8) : (((k5 - 16) >> 2) * 8 + 4);
      int pos = (row0 & ~31) + s0;
      uint2 w;
      w.x = f2bf2(fmaxf(accg[mi][nj][0], 0.f) * accf[mi][nj][0],
                  fmaxf(accg[mi][nj][1], 0.f) * accf[mi][nj][1]);
      w.y = f2bf2(fmaxf(accg[mi][nj][2], 0.f) * accf[mi][nj][2],
                  fmaxf(accg[mi][nj][3], 0.f) * accf[mi][nj][3]);
      *(uint2*)(VgTb + (size_t)n * 2048 + pos) = w;
    }
  }
}

// ---- projection GEMM 64x64 tile, grid 512: A bf16, Wp f32 fused-transpose ----
__global__ __launch_bounds__(256) void gemm_projf(
    const u16* __restrict__ A,
    const float* __restrict__ Wp,
    float* __restrict__ Cout,
    const float* __restrict__ bias) {
  __shared__ u16 lds_a[2][64 * 32];
  __shared__ u16 lds_bt[2][64 * 40];
  const int tid = threadIdx.x;
  const int wid = tid >> 6, lane = tid & 63;
  const int lrow = lane & 15, lgrp = lane >> 4;
  int bxs, bys;
  xcd_swizzle(bxs, bys);
  const int brow = bys * 64;
  const int bcol = bxs * 64;
  const int wr = wid >> 1, wc = wid & 1;

  f32x4 acc[2][2] = {};

  const int cA = wid * 64 + lane;
  const int rA = cA >> 2, col8A = (cA & 3) << 3;
  const int ng = tid & 15, kp = tid >> 4;
  const int n4 = ng << 2, kk = kp << 1;
  const int kc = kk >> 3, klo = kk & 7;

  auto stageB = [&](int k0, int bi) {
    float4 va = *(const float4*)(Wp + (size_t)(k0 + kk) * 1024 + bcol + n4);
    float4 vb = *(const float4*)(Wp + (size_t)(k0 + kk + 1) * 1024 + bcol + n4);
    const float a4[4] = {va.x, va.y, va.z, va.w};
    const float b4[4] = {vb.x, vb.y, vb.z, vb.w};
#pragma unroll
    for (int i = 0; i < 4; ++i) {
      int row = n4 + i;
      int sw = (kc ^ ((row >> 2) & 3)) << 3;
      u16* p = lds_bt[bi] + row * 40 + sw + klo;
      *(uint32_t*)p = f2bf2(a4[i], b4[i]);
    }
  };

  // prologue
  gload16(A + (size_t)(brow + rA) * 1024 + col8A, lds_a[0] + wid * 512);
  stageB(0, 0);

  for (int k0 = 0; k0 < 1024; k0 += 32) {
    const int bi = (k0 >> 5) & 1;
    __syncthreads();
    bf16x8 af[2], bfr[2];
#pragma unroll
    for (int mi = 0; mi < 2; ++mi)
      af[mi] = *(const bf16x8*)(lds_a[bi] + (wr * 32 + mi * 16 + lrow) * 32 + lgrp * 8);
#pragma unroll
    for (int nj = 0; nj < 2; ++nj) {
      int rowb = wc * 32 + nj * 16 + lrow;
      bfr[nj] = *(const bf16x8*)(lds_bt[bi] + rowb * 40 + ((lgrp ^ ((rowb >> 2) & 3)) << 3));
    }

    if (k0 < 992) {
      const int kn = k0 + 32;
      gload16(A + (size_t)(brow + rA) * 1024 + kn + col8A, lds_a[bi ^ 1] + wid * 512);
      stageB(kn, bi ^ 1);
    }

#pragma unroll
    for (int mi = 0; mi < 2; ++mi)
#pragma unroll
      for (int nj = 0; nj < 2; ++nj)
        acc[mi][nj] = __builtin_amdgcn_mfma_f32_16x16x32_bf16(af[mi], bfr[nj], acc[mi][nj], 0, 0, 0);
  }

#pragma unroll
  for (int mi = 0; mi < 2; ++mi)
#pragma unroll
    for (int nj = 0; nj < 2; ++nj)
#pragma unroll
      for (int r = 0; r < 4; ++r) {
        int row = brow + wr * 32 + mi * 16 + lgrp * 4 + r;
        int col = bcol + wc * 32 + nj * 16 + lrow;
        Cout[(size_t)row * 1024 + col] = acc[mi][nj][r] + bias[col];
      }
}

// ---- flash attention: KEY-SPLIT waves + SWAPPED QK^T, ALL-REGISTER ----
// Wave w owns keys w*32..w*32+31 of each 128-key tile, all 64 q-rows.
// K and V fragments load DIRECTLY global->reg (fragments are 16 rows x 64B
// contiguous -> fully coalesced; waves read DISJOINT slices -> no duplication,
// no LDS staging, NO barriers in the main loop). Next tile prefetched into a
// second named register buffer (hand-unrolled even/odd loop). P stays
// in-register via swapped mfma(K,Q) + VgT key permutation. LDS used once at
// the end for cross-wave O/lsum reduction. No-max softmax (log2e in Q scale).
__global__ __launch_bounds__(256) void attn_kernel(
    const u16* Qb, const u16* __restrict__ Kb,
    const u16* __restrict__ VgTb, u16* AO) {
  __shared__ float red[16384];       // [dt][qg][w][lane*4] 64KB (epilogue only)
  __shared__ float lds_ls[4][64];    // per-wave lsum partials
  const int tid = threadIdx.x, wid = tid >> 6, lane = tid & 63;
  const int lrow = lane & 15, lgrp = lane >> 4;
  const int f = blockIdx.x;
  const int h = f & 15;
  const int idx = f >> 4;
  const int qt = (idx < 16) ? idx : 47 - idx;  // f and f+256 sum to 31
  const int nt = (qt >> 1) + 1;

  // Q fragments (B-operand): qf[qg][ks], q = qt*64+qg*16+lrow, d = ks*32+lgrp*8
  bf16x8 qf[4][2];
#pragma unroll
  for (int qg = 0; qg < 4; ++qg) {
    const u16* qp = Qb + (size_t)(qt * 64 + qg * 16 + lrow) * 1024 + h * 64 + lgrp * 8;
    qf[qg][0] = *(const bf16x8*)(qp);
    qf[qg][1] = *(const bf16x8*)(qp + 32);
  }

  const u16* Kh = Kb + h * 64;                      // row stride 1024
  const u16* Vh = VgTb + (size_t)(h * 64) * 2048;   // row stride 2048
  const int krow0 = wid * 32 + lrow;                // + nj2*16
  const int kcol = lgrp * 8;                        // + ks*32
  const int vcolw = wid * 32 + lgrp * 8;

  f32x4 oacc[4][4] = {};   // [qg][dt]
  float lsum[4] = {0.f, 0.f, 0.f, 0.f};

  bf16x8 a00, a10, a01, a11, av0, av1, av2, av3;  // buffer A (k[ks][nj2], v[dt])
  bf16x8 b00, b10, b01, b11, bv0, bv1, bv2, bv3;  // buffer B

  auto compute = [&](int t, bf16x8& k00, bf16x8& k10, bf16x8& k01, bf16x8& k11,
                     bf16x8& v0, bf16x8& v1, bf16x8& v2, bf16x8& v3) {
    f32x4 sacc[4][2] = {};
#pragma unroll
    for (int qg = 0; qg < 4; ++qg) {
      sacc[qg][0] = __builtin_amdgcn_mfma_f32_16x16x32_bf16(k00, qf[qg][0], sacc[qg][0], 0, 0, 0);
      sacc[qg][0] = __builtin_amdgcn_mfma_f32_16x16x32_bf16(k10, qf[qg][1], sacc[qg][0], 0, 0, 0);
      sacc[qg][1] = __builtin_amdgcn_mfma_f32_16x16x32_bf16(k01, qf[qg][0], sacc[qg][1], 0, 0, 0);
      sacc[qg][1] = __builtin_amdgcn_mfma_f32_16x16x32_bf16(k11, qf[qg][1], sacc[qg][1], 0, 0, 0);
    }
    const bool last = (t == nt - 1);
#pragma unroll
    for (int qg = 0; qg < 4; ++qg) {
#pragma unroll
      for (int nj2 = 0; nj2 < 2; ++nj2) {
#pragma unroll
        for (int r = 0; r < 4; ++r) {
          float p;
          if (last) {
            int key = t * 128 + wid * 32 + nj2 * 16 + lgrp * 4 + r;
            int srow = qt * 64 + qg * 16 + lrow;
            p = (key > srow) ? 0.f : exp2f(sacc[qg][nj2][r]);
          } else {
            p = exp2f(sacc[qg][nj2][r]);
          }
          sacc[qg][nj2][r] = p;
          lsum[qg] += p;
        }
      }
    }
#pragma unroll
    for (int qg = 0; qg < 4; ++qg) {
      union { uint32_t u[4]; bf16x8 v; } pa;
      pa.u[0] = f2bf2(sacc[qg][0][0], sacc[qg][0][1]);
      pa.u[1] = f2bf2(sacc[qg][0][2], sacc[qg][0][3]);
      pa.u[2] = f2bf2(sacc[qg][1][0], sacc[qg][1][1]);
      pa.u[3] = f2bf2(sacc[qg][1][2], sacc[qg][1][3]);
      oacc[qg][0] = __builtin_amdgcn_mfma_f32_16x16x32_bf16(pa.v, v0, oacc[qg][0], 0, 0, 0);
      oacc[qg][1] = __builtin_amdgcn_mfma_f32_16x16x32_bf16(pa.v, v1, oacc[qg][1], 0, 0, 0);
      oacc[qg][2] = __builtin_amdgcn_mfma_f32_16x16x32_bf16(pa.v, v2, oacc[qg][2], 0, 0, 0);
      oacc[qg][3] = __builtin_amdgcn_mfma_f32_16x16x32_bf16(pa.v, v3, oacc[qg][3], 0, 0, 0);
    }
  };

  // prologue: load tile 0 into buffer A
  {
    const u16* kb = Kh + (size_t)(krow0) * 1024 + kcol;
    a00 = *(const bf16x8*)(kb);
    a10 = *(const bf16x8*)(kb + 32);
    a01 = *(const bf16x8*)(kb + 16 * 1024);
    a11 = *(const bf16x8*)(kb + 16 * 1024 + 32);
    const u16* vb = Vh + (size_t)(lrow) * 2048 + vcolw;
    av0 = *(const bf16x8*)(vb);
    av1 = *(const bf16x8*)(vb + 16 * 2048);
    av2 = *(const bf16x8*)(vb + 32 * 2048);
    av3 = *(const bf16x8*)(vb + 48 * 2048);
  }

  int t = 0;
  while (true) {
    // compute buffer A for tile t, prefetch t+1 into B
    if (t + 1 < nt) {
      const u16* kb = Kh + (size_t)((t + 1) * 128 + krow0) * 1024 + kcol;
      b00 = *(const bf16x8*)(kb);
      b10 = *(const bf16x8*)(kb + 32);
      b01 = *(const bf16x8*)(kb + 16 * 1024);
      b11 = *(const bf16x8*)(kb + 16 * 1024 + 32);
      const u16* vb = Vh + (size_t)(lrow) * 2048 + (t + 1) * 128 + vcolw;
      bv0 = *(const bf16x8*)(vb);
      bv1 = *(const bf16x8*)(vb + 16 * 2048);
      bv2 = *(const bf16x8*)(vb + 32 * 2048);
      bv3 = *(const bf16x8*)(vb + 48 * 2048);
    }
    compute(t, a00, a10, a01, a11, av0, av1, av2, av3);
    ++t;
    if (t >= nt) break;
    // compute buffer B for tile t, prefetch t+1 into A
    if (t + 1 < nt) {
      const u16* kb = Kh + (size_t)((t + 1) * 128 + krow0) * 1024 + kcol;
      a00 = *(const bf16x8*)(kb);
      a10 = *(const bf16x8*)(kb + 32);
      a01 = *(const bf16x8*)(kb + 16 * 1024);
      a11 = *(const bf16x8*)(kb + 16 * 1024 + 32);
      const u16* vb = Vh + (size_t)(lrow) * 2048 + (t + 1) * 128 + vcolw;
      av0 = *(const bf16x8*)(vb);
      av1 = *(const bf16x8*)(vb + 16 * 2048);
      av2 = *(const bf16x8*)(vb + 32 * 2048);
      av3 = *(const bf16x8*)(vb + 48 * 2048);
    }
    compute(t, b00, b10, b01, b11, bv0, bv1, bv2, bv3);
    ++t;
    if (t >= nt) break;
  }

  // lsum: reduce over the 4 lgrp groups, publish per wave
#pragma unroll
  for (int qg = 0; qg < 4; ++qg) {
    lsum[qg] += __shfl_xor(lsum[qg], 16);
    lsum[qg] += __shfl_xor(lsum[qg], 32);
  }
  if (lgrp == 0) {
#pragma unroll
    for (int qg = 0; qg < 4; ++qg) lds_ls[wid][qg * 16 + lrow] = lsum[qg];
  }

  // O partials: red[dt][qg][w][lane]
#pragma unroll
  for (int qg = 0; qg < 4; ++qg)
#pragma unroll
    for (int dt = 0; dt < 4; ++dt)
      *(f32x4*)(red + dt * 4096 + qg * 1024 + wid * 256 + lane * 4) = oacc[qg][dt];
  __syncthreads();

#pragma unroll
  for (int qg = 0; qg < 4; ++qg) {
    f32x4 s = *(const f32x4*)(red + wid * 4096 + qg * 1024 + 0 * 256 + lane * 4);
#pragma unroll
    for (int w = 1; w < 4; ++w) {
      f32x4 x = *(const f32x4*)(red + wid * 4096 + qg * 1024 + w * 256 + lane * 4);
      s[0] += x[0]; s[1] += x[1]; s[2] += x[2]; s[3] += x[3];
    }
#pragma unroll
    for (int r = 0; r < 4; ++r) {
      int q = qg * 16 + lgrp * 4 + r;
      float ls = lds_ls[0][q] + lds_ls[1][q] + lds_ls[2][q] + lds_ls[3][q];
      AO[(size_t)(qt * 64 + q) * 1024 + h * 64 + wid * 16 + lrow] = f2bf(s[r] / ls);
    }
  }
}

extern "C" void kernel_launch(void* const* d_in, const int* in_sizes, int n_in,
                              void* d_out, int out_size, void* d_ws, size_t ws_size,
                              hipStream_t stream) {
  const float* hidden    = (const float*)d_in[0];
  // d_in[1] = mask (causal tril by construction; not read)
  const int*   layer_idx = (const int*)d_in[2];
  const float* W_attn    = (const float*)d_in[3];
  const float* b_attn    = (const float*)d_in[4];
  const float* W_proj    = (const float*)d_in[5];
  const float* b_proj    = (const float*)d_in[6];
  const float* W_v_ff    = (const float*)d_in[7];
  const float* W_v_gate  = (const float*)d_in[8];

  // ws peak: 4 MiB. d_out quarters (4MB each) carry intermediates:
  //  A: V0 -> K0 -> Q1/AO1 -> (f32 out)     B: VgT0 -> K1 -> (f32 out)
  //  C: V1 -> WqkT -> (f32 out)             D: WvT -> VgT1 -> (f32 out)
  //  ws: WgT|WfT -> Q0/AO0
  const size_t MB = 1ull << 20;
  char* ob = (char*)d_out;
  u16* QA = (u16*)(ob);
  u16* QB = (u16*)(ob + 4 * MB);
  u16* QC = (u16*)(ob + 8 * MB);
  u16* QD = (u16*)(ob + 12 * MB);
  u16* WS  = (u16*)d_ws;
  u16* WfT = WS + 1024 * 1024;

  const float* hid0 = hidden;
  const float* hid1 = hidden + (size_t)2048 * 1024;

  // 1. WvT -> D[0,2M), WgT -> ws[0,2M), WfT -> ws[2,4M)
  prep3_kernel<<<dim3(16, 16, 3), 256, 0, stream>>>(W_attn, W_v_gate, W_v_ff, QD, WS, WfT);
  // 2. V (both batches) = hidden @ WvT + bv -> A / C
  gemm_hA<1><<<dim3(8, 64), 256, 0, stream>>>(hidden, QD, QA, nullptr, b_attn + 2048, nullptr);
  // 3. VgT (both, key-permuted) = gate(V) -> B / D (WvT dead)
  gemm_gate<<<dim3(8, 64), 256, 0, stream>>>(QA, WS, WfT, QB);
  // 4. WqkT -> C (V1 dead)
  transpose_bf16_kernel<<<dim3(16, 32), 256, 0, stream>>>(W_attn, QC, 3072, 0);
  // 5. Q0 -> ws (WgT/WfT dead), K0 -> A (V0 dead)
  gemm_hA<0><<<dim3(16, 32), 256, 0, stream>>>(hid0, QC, WS, QA, b_attn, layer_idx);
  // 6. attn b0: AO0 in-place over Q0 (ws)
  attn_kernel<<<512, 256, 0, stream>>>(WS, QA, QB, WS);
  // 7. Q1 -> A (K0 dead), K1 -> B (VgT0 dead)
  gemm_hA<0><<<dim3(16, 32), 256, 0, stream>>>(hid1, QC, QA, QB, b_attn, layer_idx);
  // 8. attn b1: AO1 in-place over Q1 (A)
  attn_kernel<<<512, 256, 0, stream>>>(QA, QB, QD, QA);
  // 9. proj b1: AO1@A -> out rows [2048,4096) = C+D (WqkT/VgT1 dead)
  gemm_projf<<<dim3(16, 32), 256, 0, stream>>>(QA, W_proj, (float*)d_out + (size_t)2048 * 1024, b_proj);
  // 10. proj b0: AO0@ws -> out rows [0,2048) = A+B (AO1 consumed by step 9)
  gemm_projf<<<dim3(16, 32), 256, 0, stream>>>(WS, W_proj, (float*)d_out, b_proj);
}

// Round 19
// 213.754 us; speedup vs baseline: 1.1188x; 1.1188x over previous
//
#include <hip/hip_runtime.h>
#include <hip/hip_bf16.h>
#include <cstdint>
#include <cstddef>

typedef unsigned short u16;
typedef __bf16 bf16x8 __attribute__((ext_vector_type(8)));
typedef float f32x4 __attribute__((ext_vector_type(4)));

#define LOG2E 1.44269504088896340736f

// packed f32x2 -> bf16x2 (RTNE) in ONE VALU inst; low16=lo, high16=hi
__device__ __forceinline__ uint32_t f2bf2(float lo, float hi) {
  uint32_t r;
  asm("v_cvt_pk_bf16_f32 %0, %1, %2" : "=v"(r) : "v"(lo), "v"(hi));
  return r;
}
__device__ __forceinline__ u16 f2bf(float f) { return (u16)f2bf2(f, f); }

__device__ __forceinline__ void gload16(const u16* g, u16* l) {
  __builtin_amdgcn_global_load_lds(
      (const __attribute__((address_space(1))) void*)g,
      (__attribute__((address_space(3))) void*)l, 16, 0, 0);
}

// XCD-chunked block swizzle
__device__ __forceinline__ void xcd_swizzle(int& bx, int& by) {
  const int gx = gridDim.x;
  const int nwg = gx * gridDim.y;
  const int bid = blockIdx.y * gx + blockIdx.x;
  const int s = (bid & 7) * (nwg >> 3) + (bid >> 3);
  bx = s % gx;
  by = s / gx;
}

// ---- fp32 (1024 x ld) column-stripe -> bf16 transposed slice ----
__global__ __launch_bounds__(256) void transpose_bf16_kernel(
    const float* __restrict__ src, u16* __restrict__ dst, int ld, int c0) {
  __shared__ u16 tile[64][65];
  const int r0 = blockIdx.x * 64, cl0 = blockIdx.y * 64;
  const int tid = threadIdx.x;
#pragma unroll
  for (int i = 0; i < 16; ++i) {
    int idx = i * 256 + tid;
    int r = idx >> 6, c = idx & 63;
    tile[c][r] = f2bf(src[(size_t)(r0 + r) * ld + c0 + cl0 + c]);
  }
  __syncthreads();
#pragma unroll
  for (int i = 0; i < 16; ++i) {
    int idx = i * 256 + tid;
    int c = idx >> 6, r = idx & 63;
    dst[(size_t)(cl0 + c) * 1024 + r0 + r] = tile[c][r];
  }
}

// ---- 3 weight transposes in one launch ----
__global__ __launch_bounds__(256) void prep3_kernel(
    const float* __restrict__ Wa, const float* __restrict__ Wg,
    const float* __restrict__ Wf,
    u16* __restrict__ dv, u16* __restrict__ dg, u16* __restrict__ df) {
  __shared__ u16 tile[64][65];
  const int z = blockIdx.z;
  const float* src = (z == 0) ? Wa : (z == 1) ? Wg : Wf;
  u16* dst = (z == 0) ? dv : (z == 1) ? dg : df;
  const int ld = (z == 0) ? 3072 : 1024;
  const int c0 = (z == 0) ? 2048 : 0;
  const int r0 = blockIdx.x * 64, cl0 = blockIdx.y * 64;
  const int tid = threadIdx.x;
#pragma unroll
  for (int i = 0; i < 16; ++i) {
    int idx = i * 256 + tid;
    int r = idx >> 6, c = idx & 63;
    tile[c][r] = f2bf(src[(size_t)(r0 + r) * ld + c0 + cl0 + c]);
  }
  __syncthreads();
#pragma unroll
  for (int i = 0; i < 16; ++i) {
    int idx = i * 256 + tid;
    int c = idx >> 6, r = idx & 63;
    dst[(size_t)(cl0 + c) * 1024 + r0 + r] = tile[c][r];
  }
}

// ---- GEMM 64x128 tile, A = f32 (reg-staged + bf16 convert), Bt bf16 ----
// EPI 0: N=2048: col<1024 -> O0 (+bias, *scale*log2e); col>=1024 -> O1 (+bias)
// EPI 1: N=1024: O0 bf16, +bias; rows GLOBAL 0..4095, batch stride 4194304 u16
template <int EPI>
__global__ __launch_bounds__(256) void gemm_hA(
    const float* __restrict__ A,
    const u16* __restrict__ Bt,
    u16* __restrict__ O0, u16* __restrict__ O1,
    const float* __restrict__ bias,
    const int* __restrict__ layer_idx) {
  __shared__ u16 lds_a[2][64 * 40];
  __shared__ u16 lds_b[2][128 * 32];
  const int tid = threadIdx.x;
  const int wid = tid >> 6, lane = tid & 63;
  const int lrow = lane & 15, lgrp = lane >> 4;
  int bxs, bys;
  xcd_swizzle(bxs, bys);
  const int brow = bys * 64;
  const int bcol = bxs * 128;
  const int wr = wid >> 1, wc = wid & 1;

  f32x4 acc[2][4] = {};

  const int wchunk0 = wid, wchunk1 = 4 + wid;
  const int cB0 = wchunk0 * 64 + lane, cB1 = wchunk1 * 64 + lane;
  const int rB0 = cB0 >> 2, col8B0 = (cB0 & 3) << 3;
  const int rB1 = cB1 >> 2, col8B1 = (cB1 & 3) << 3;

  // prologue
  gload16(Bt + (size_t)(bcol + rB0) * 1024 + col8B0, lds_b[0] + wchunk0 * 512);
  gload16(Bt + (size_t)(bcol + rB1) * 1024 + col8B1, lds_b[0] + wchunk1 * 512);
  {
    float4 v[2];
#pragma unroll
    for (int j = 0; j < 2; ++j) {
      int idx = j * 256 + tid;
      int m = idx >> 3, k4 = (idx & 7) << 2;
      v[j] = *(const float4*)(A + (size_t)(brow + m) * 1024 + k4);
    }
#pragma unroll
    for (int j = 0; j < 2; ++j) {
      int idx = j * 256 + tid;
      int m = idx >> 3, k4 = (idx & 7) << 2;
      uint2 w;
      w.x = f2bf2(v[j].x, v[j].y);
      w.y = f2bf2(v[j].z, v[j].w);
      *(uint2*)(lds_a[0] + m * 40 + k4) = w;
    }
  }

  for (int k0 = 0; k0 < 1024; k0 += 32) {
    const int bi = (k0 >> 5) & 1;
    __syncthreads();
    bf16x8 af[2], bfr[4];
#pragma unroll
    for (int mi = 0; mi < 2; ++mi)
      af[mi] = *(const bf16x8*)(lds_a[bi] + (wr * 32 + mi * 16 + lrow) * 40 + lgrp * 8);
#pragma unroll
    for (int nj = 0; nj < 4; ++nj)
      bfr[nj] = *(const bf16x8*)(lds_b[bi] + (wc * 64 + nj * 16 + lrow) * 32 + lgrp * 8);

    float4 v[2];
    if (k0 < 992) {
      const int kn = k0 + 32;
      gload16(Bt + (size_t)(bcol + rB0) * 1024 + kn + col8B0, lds_b[bi ^ 1] + wchunk0 * 512);
      gload16(Bt + (size_t)(bcol + rB1) * 1024 + kn + col8B1, lds_b[bi ^ 1] + wchunk1 * 512);
#pragma unroll
      for (int j = 0; j < 2; ++j) {
        int idx = j * 256 + tid;
        int m = idx >> 3, k4 = (idx & 7) << 2;
        v[j] = *(const float4*)(A + (size_t)(brow + m) * 1024 + kn + k4);
      }
    }

#pragma unroll
    for (int mi = 0; mi < 2; ++mi)
#pragma unroll
      for (int nj = 0; nj < 4; ++nj)
        acc[mi][nj] = __builtin_amdgcn_mfma_f32_16x16x32_bf16(af[mi], bfr[nj], acc[mi][nj], 0, 0, 0);

    if (k0 < 992) {
#pragma unroll
      for (int j = 0; j < 2; ++j) {
        int idx = j * 256 + tid;
        int m = idx >> 3, k4 = (idx & 7) << 2;
        uint2 w;
        w.x = f2bf2(v[j].x, v[j].y);
        w.y = f2bf2(v[j].z, v[j].w);
        *(uint2*)(lds_a[bi ^ 1] + m * 40 + k4) = w;
      }
    }
  }

  float scale = 1.0f;
  if (EPI == 0) scale = 0.125f * LOG2E / (1.0f + (float)(*layer_idx));

#pragma unroll
  for (int mi = 0; mi < 2; ++mi) {
#pragma unroll
    for (int nj = 0; nj < 4; ++nj) {
#pragma unroll
      for (int r = 0; r < 4; ++r) {
        int row = brow + wr * 32 + mi * 16 + lgrp * 4 + r;
        int col = bcol + wc * 64 + nj * 16 + lrow;
        float vv = acc[mi][nj][r] + bias[col];
        if (EPI == 0) {
          if (col < 1024) {
            O0[(size_t)row * 1024 + col] = f2bf(vv * scale);
          } else {
            O1[(size_t)row * 1024 + (col - 1024)] = f2bf(vv);
          }
        } else {
          size_t oidx = (size_t)(row >> 11) * 4194304 + (size_t)(row & 2047) * 1024 + col;
          O0[oidx] = f2bf(vv);
        }
      }
    }
  }
}

// ---- fused gate/ff GEMM, 64x128 tile, both batches ----
// Writes VgT with key positions PERMUTED within each 32-key group so that
// attention's PV B-operand slot s holds key pi(s):
//   pi(s): j=s&7, g=s>>3; j<4 -> key g*4+j ; j>=4 -> key 16+g*4+(j-4)
__global__ __launch_bounds__(256) void gemm_gate(
    const u16* __restrict__ A,
    const u16* __restrict__ Bg, const u16* __restrict__ Bf,
    u16* __restrict__ VgT) {
  __shared__ u16 lds_a[2][64 * 32];
  __shared__ u16 lds_g[2][128 * 32];
  __shared__ u16 lds_f[2][128 * 32];
  const int tid = threadIdx.x;
  const int wid = tid >> 6, lane = tid & 63;
  const int lrow = lane & 15, lgrp = lane >> 4;
  int bxs, bys;
  xcd_swizzle(bxs, bys);
  const int browg = bys * 64;
  const int batch = browg >> 11;
  const int brow = browg & 2047;
  const u16* Ab = A + (size_t)batch * 4194304;
  u16* VgTb = VgT + (size_t)batch * 4194304;
  const int bcol = bxs * 128;
  const int wr = wid >> 1, wc = wid & 1;

  f32x4 accg[2][4] = {};
  f32x4 accf[2][4] = {};

  const int wchunk0 = wid, wchunk1 = 4 + wid;
  const int cA = wchunk0 * 64 + lane;
  const int rA = cA >> 2, col8A = (cA & 3) << 3;
  const int cB0 = wchunk0 * 64 + lane, cB1 = wchunk1 * 64 + lane;
  const int rB0 = cB0 >> 2, col8B0 = (cB0 & 3) << 3;
  const int rB1 = cB1 >> 2, col8B1 = (cB1 & 3) << 3;

  auto stage = [&](int k0, int bi) {
    gload16(Ab + (size_t)(brow + rA) * 1024 + k0 + col8A, lds_a[bi] + wchunk0 * 512);
    gload16(Bg + (size_t)(bcol + rB0) * 1024 + k0 + col8B0, lds_g[bi] + wchunk0 * 512);
    gload16(Bg + (size_t)(bcol + rB1) * 1024 + k0 + col8B1, lds_g[bi] + wchunk1 * 512);
    gload16(Bf + (size_t)(bcol + rB0) * 1024 + k0 + col8B0, lds_f[bi] + wchunk0 * 512);
    gload16(Bf + (size_t)(bcol + rB1) * 1024 + k0 + col8B1, lds_f[bi] + wchunk1 * 512);
  };

  stage(0, 0);
  for (int k0 = 0; k0 < 1024; k0 += 32) {
    const int bi = (k0 >> 5) & 1;
    __syncthreads();
    bf16x8 af[2], bg[4], bff[4];
#pragma unroll
    for (int mi = 0; mi < 2; ++mi)
      af[mi] = *(const bf16x8*)(lds_a[bi] + (wr * 32 + mi * 16 + lrow) * 32 + lgrp * 8);
#pragma unroll
    for (int nj = 0; nj < 4; ++nj) {
      bg[nj]  = *(const bf16x8*)(lds_g[bi] + (wc * 64 + nj * 16 + lrow) * 32 + lgrp * 8);
      bff[nj] = *(const bf16x8*)(lds_f[bi] + (wc * 64 + nj * 16 + lrow) * 32 + lgrp * 8);
    }
    if (k0 < 992) stage(k0 + 32, bi ^ 1);
#pragma unroll
    for (int mi = 0; mi < 2; ++mi)
#pragma unroll
      for (int nj = 0; nj < 4; ++nj) {
        accg[mi][nj] = __builtin_amdgcn_mfma_f32_16x16x32_bf16(af[mi], bg[nj],  accg[mi][nj], 0, 0, 0);
        accf[mi][nj] = __builtin_amdgcn_mfma_f32_16x16x32_bf16(af[mi], bff[nj], accf[mi][nj], 0, 0, 0);
      }
  }

#pragma unroll
  for (int mi = 0; mi < 2; ++mi) {
#pragma unroll
    for (int nj = 0; nj < 4; ++nj) {
      int row0 = brow + wr * 32 + mi * 16 + lgrp * 4;  // key position, mult of 4
      int n = bcol + wc * 64 + nj * 16 + lrow;
      int k5 = row0 & 31;
      int s0 = (k5 < 16) ? ((k5 >> 2) * 8) : (((k5 - 16) >> 2) * 8 + 4);
      int pos = (row0 & ~31) + s0;
      uint2 w;
      w.x = f2bf2(fmaxf(accg[mi][nj][0], 0.f) * accf[mi][nj][0],
                  fmaxf(accg[mi][nj][1], 0.f) * accf[mi][nj][1]);
      w.y = f2bf2(fmaxf(accg[mi][nj][2], 0.f) * accf[mi][nj][2],
                  fmaxf(accg[mi][nj][3], 0.f) * accf[mi][nj][3]);
      *(uint2*)(VgTb + (size_t)n * 2048 + pos) = w;
    }
  }
}

// ---- projection GEMM 64x64 tile, grid 512: A bf16, Wp f32 fused-transpose ----
__global__ __launch_bounds__(256) void gemm_projf(
    const u16* __restrict__ A,
    const float* __restrict__ Wp,
    float* __restrict__ Cout,
    const float* __restrict__ bias) {
  __shared__ u16 lds_a[2][64 * 32];
  __shared__ u16 lds_bt[2][64 * 40];
  const int tid = threadIdx.x;
  const int wid = tid >> 6, lane = tid & 63;
  const int lrow = lane & 15, lgrp = lane >> 4;
  int bxs, bys;
  xcd_swizzle(bxs, bys);
  const int brow = bys * 64;
  const int bcol = bxs * 64;
  const int wr = wid >> 1, wc = wid & 1;

  f32x4 acc[2][2] = {};

  const int cA = wid * 64 + lane;
  const int rA = cA >> 2, col8A = (cA & 3) << 3;
  const int ng = tid & 15, kp = tid >> 4;
  const int n4 = ng << 2, kk = kp << 1;
  const int kc = kk >> 3, klo = kk & 7;

  auto stageB = [&](int k0, int bi) {
    float4 va = *(const float4*)(Wp + (size_t)(k0 + kk) * 1024 + bcol + n4);
    float4 vb = *(const float4*)(Wp + (size_t)(k0 + kk + 1) * 1024 + bcol + n4);
    const float a4[4] = {va.x, va.y, va.z, va.w};
    const float b4[4] = {vb.x, vb.y, vb.z, vb.w};
#pragma unroll
    for (int i = 0; i < 4; ++i) {
      int row = n4 + i;
      int sw = (kc ^ ((row >> 2) & 3)) << 3;
      u16* p = lds_bt[bi] + row * 40 + sw + klo;
      *(uint32_t*)p = f2bf2(a4[i], b4[i]);
    }
  };

  // prologue
  gload16(A + (size_t)(brow + rA) * 1024 + col8A, lds_a[0] + wid * 512);
  stageB(0, 0);

  for (int k0 = 0; k0 < 1024; k0 += 32) {
    const int bi = (k0 >> 5) & 1;
    __syncthreads();
    bf16x8 af[2], bfr[2];
#pragma unroll
    for (int mi = 0; mi < 2; ++mi)
      af[mi] = *(const bf16x8*)(lds_a[bi] + (wr * 32 + mi * 16 + lrow) * 32 + lgrp * 8);
#pragma unroll
    for (int nj = 0; nj < 2; ++nj) {
      int rowb = wc * 32 + nj * 16 + lrow;
      bfr[nj] = *(const bf16x8*)(lds_bt[bi] + rowb * 40 + ((lgrp ^ ((rowb >> 2) & 3)) << 3));
    }

    if (k0 < 992) {
      const int kn = k0 + 32;
      gload16(A + (size_t)(brow + rA) * 1024 + kn + col8A, lds_a[bi ^ 1] + wid * 512);
      stageB(kn, bi ^ 1);
    }

#pragma unroll
    for (int mi = 0; mi < 2; ++mi)
#pragma unroll
      for (int nj = 0; nj < 2; ++nj)
        acc[mi][nj] = __builtin_amdgcn_mfma_f32_16x16x32_bf16(af[mi], bfr[nj], acc[mi][nj], 0, 0, 0);
  }

#pragma unroll
  for (int mi = 0; mi < 2; ++mi)
#pragma unroll
    for (int nj = 0; nj < 2; ++nj)
#pragma unroll
      for (int r = 0; r < 4; ++r) {
        int row = brow + wr * 32 + mi * 16 + lgrp * 4 + r;
        int col = bcol + wc * 32 + nj * 16 + lrow;
        Cout[(size_t)row * 1024 + col] = acc[mi][nj][r] + bias[col];
      }
}

// ---- flash attention: KEY-SPLIT waves + SWAPPED QK^T, in-register P ----
// Block = 64 q-rows x 128-key tiles; wave w owns keys w*32..w*32+31 of each
// tile but ALL 64 q (4 q-groups of 16). QK computed as mfma(K,Q) so each
// lane holds P for q=lane&15 -- exactly the PV A-fragment layout given VgT's
// key permutation (see gemm_gate). P never touches LDS. K/V staged in dbuf
// LDS, 1 barrier/tile. End: O partials + lsum reduced across waves through
// the (dead) K/V LDS. No-max softmax (log2e in Q scale).
__global__ __launch_bounds__(256) void attn_kernel(
    const u16* Qb, const u16* __restrict__ Kb,
    const u16* __restrict__ VgTb, u16* AO) {
  __shared__ u16 lds_kv[2][16384];   // per buf: K[128*64] | V[64*128] (32KB)
  __shared__ float lds_ls[4][64];    // per-wave lsum partials
  const int tid = threadIdx.x, wid = tid >> 6, lane = tid & 63;
  const int lrow = lane & 15, lgrp = lane >> 4;
  const int f = blockIdx.x;
  const int h = f & 15;
  const int idx = f >> 4;
  const int qt = (idx < 16) ? idx : 47 - idx;  // f and f+256 sum to 31
  const int nt = (qt >> 1) + 1;

  // Q fragments (B-operand): qf[qg][ks], q = qt*64+qg*16+lrow, d = ks*32+lgrp*8
  bf16x8 qf[4][2];
#pragma unroll
  for (int qg = 0; qg < 4; ++qg) {
    const u16* qp = Qb + (size_t)(qt * 64 + qg * 16 + lrow) * 1024 + h * 64 + lgrp * 8;
    qf[qg][0] = *(const bf16x8*)(qp);
    qf[qg][1] = *(const bf16x8*)(qp + 32);
  }

  int krow[4], kch[4], vrow[4], vch[4];
#pragma unroll
  for (int i = 0; i < 4; ++i) {
    int c = i * 256 + tid;
    krow[i] = c >> 3; kch[i] = c & 7;
    vrow[i] = c >> 4; vch[i] = c & 15;
  }
  bf16x8 kreg[4], vreg[4];

  auto stage_load = [&](int t) {
#pragma unroll
    for (int i = 0; i < 4; ++i) {
      kreg[i] = *(const bf16x8*)(Kb + (size_t)(t * 128 + krow[i]) * 1024 + h * 64 + kch[i] * 8);
      vreg[i] = *(const bf16x8*)(VgTb + (size_t)(h * 64 + vrow[i]) * 2048 + t * 128 + vch[i] * 8);
    }
  };
  auto stage_write = [&](int bi) {
#pragma unroll
    for (int i = 0; i < 4; ++i) {
      *(bf16x8*)(lds_kv[bi] + krow[i] * 64 + ((kch[i] ^ (krow[i] & 7)) << 3)) = kreg[i];
      *(bf16x8*)(lds_kv[bi] + 8192 + vrow[i] * 128 + ((vch[i] ^ (vrow[i] & 7)) << 3)) = vreg[i];
    }
  };

  stage_load(0);
  stage_write(0);
  __syncthreads();

  f32x4 oacc[4][4] = {};   // [qg][dt]: lane holds q=qg*16+lgrp*4+r, d=dt*16+lrow
  float lsum[4] = {0.f, 0.f, 0.f, 0.f};  // per lane: q = qg*16+lrow

  for (int t = 0; t < nt; ++t) {
    const int bi = t & 1;
    if (t + 1 < nt) stage_load(t + 1);
    const u16* lk = lds_kv[bi];
    const u16* lv = lds_kv[bi] + 8192;

    bf16x8 kf[2][2];
#pragma unroll
    for (int ks = 0; ks < 2; ++ks)
#pragma unroll
      for (int nj2 = 0; nj2 < 2; ++nj2) {
        int row = wid * 32 + nj2 * 16 + lrow;
        kf[ks][nj2] = *(const bf16x8*)(lk + row * 64 + (((ks * 4 + lgrp) ^ (lrow & 7)) << 3));
      }
    bf16x8 vf[4];
#pragma unroll
    for (int dt = 0; dt < 4; ++dt)
      vf[dt] = *(const bf16x8*)(lv + (dt * 16 + lrow) * 128 + (((wid * 4 + lgrp) ^ (lrow & 7)) << 3));

    f32x4 sacc[4][2] = {};
#pragma unroll
    for (int qg = 0; qg < 4; ++qg)
#pragma unroll
      for (int ks = 0; ks < 2; ++ks)
#pragma unroll
        for (int nj2 = 0; nj2 < 2; ++nj2)
          sacc[qg][nj2] = __builtin_amdgcn_mfma_f32_16x16x32_bf16(kf[ks][nj2], qf[qg][ks], sacc[qg][nj2], 0, 0, 0);

    const bool last = (t == nt - 1);
#pragma unroll
    for (int qg = 0; qg < 4; ++qg) {
#pragma unroll
      for (int nj2 = 0; nj2 < 2; ++nj2) {
#pragma unroll
        for (int r = 0; r < 4; ++r) {
          float p;
          if (last) {
            int key = t * 128 + wid * 32 + nj2 * 16 + lgrp * 4 + r;
            int srow = qt * 64 + qg * 16 + lrow;
            p = (key > srow) ? 0.f : exp2f(sacc[qg][nj2][r]);
          } else {
            p = exp2f(sacc[qg][nj2][r]);
          }
          sacc[qg][nj2][r] = p;
          lsum[qg] += p;
        }
      }
    }

#pragma unroll
    for (int qg = 0; qg < 4; ++qg) {
      union { uint32_t u[4]; bf16x8 v; } pa;
      pa.u[0] = f2bf2(sacc[qg][0][0], sacc[qg][0][1]);
      pa.u[1] = f2bf2(sacc[qg][0][2], sacc[qg][0][3]);
      pa.u[2] = f2bf2(sacc[qg][1][0], sacc[qg][1][1]);
      pa.u[3] = f2bf2(sacc[qg][1][2], sacc[qg][1][3]);
#pragma unroll
      for (int dt = 0; dt < 4; ++dt)
        oacc[qg][dt] = __builtin_amdgcn_mfma_f32_16x16x32_bf16(pa.v, vf[dt], oacc[qg][dt], 0, 0, 0);
    }

    if (t + 1 < nt) stage_write(bi ^ 1);
    __syncthreads();
  }

  // lsum: reduce over the 4 lgrp groups, publish per wave
#pragma unroll
  for (int qg = 0; qg < 4; ++qg) {
    lsum[qg] += __shfl_xor(lsum[qg], 16);
    lsum[qg] += __shfl_xor(lsum[qg], 32);
  }
  if (lgrp == 0) {
#pragma unroll
    for (int qg = 0; qg < 4; ++qg) lds_ls[wid][qg * 16 + lrow] = lsum[qg];
  }

  // O partials through dead K/V LDS: red[dt][qg][w][lane]
  float* red = (float*)lds_kv;
#pragma unroll
  for (int qg = 0; qg < 4; ++qg)
#pragma unroll
    for (int dt = 0; dt < 4; ++dt)
      *(f32x4*)(red + dt * 4096 + qg * 1024 + wid * 256 + lane * 4) = oacc[qg][dt];
  __syncthreads();

#pragma unroll
  for (int qg = 0; qg < 4; ++qg) {
    f32x4 s = *(const f32x4*)(red + wid * 4096 + qg * 1024 + 0 * 256 + lane * 4);
#pragma unroll
    for (int w = 1; w < 4; ++w) {
      f32x4 x = *(const f32x4*)(red + wid * 4096 + qg * 1024 + w * 256 + lane * 4);
      s[0] += x[0]; s[1] += x[1]; s[2] += x[2]; s[3] += x[3];
    }
#pragma unroll
    for (int r = 0; r < 4; ++r) {
      int q = qg * 16 + lgrp * 4 + r;
      float ls = lds_ls[0][q] + lds_ls[1][q] + lds_ls[2][q] + lds_ls[3][q];
      AO[(size_t)(qt * 64 + q) * 1024 + h * 64 + wid * 16 + lrow] = f2bf(s[r] / ls);
    }
  }
}

extern "C" void kernel_launch(void* const* d_in, const int* in_sizes, int n_in,
                              void* d_out, int out_size, void* d_ws, size_t ws_size,
                              hipStream_t stream) {
  const float* hidden    = (const float*)d_in[0];
  // d_in[1] = mask (causal tril by construction; not read)
  const int*   layer_idx = (const int*)d_in[2];
  const float* W_attn    = (const float*)d_in[3];
  const float* b_attn    = (const float*)d_in[4];
  const float* W_proj    = (const float*)d_in[5];
  const float* b_proj    = (const float*)d_in[6];
  const float* W_v_ff    = (const float*)d_in[7];
  const float* W_v_gate  = (const float*)d_in[8];

  // ws peak: 4 MiB. d_out quarters (4MB each) carry intermediates:
  //  A: V0 -> K0 -> Q1/AO1 -> (f32 out)     B: VgT0 -> K1 -> (f32 out)
  //  C: V1 -> WqkT -> (f32 out)             D: WvT -> VgT1 -> (f32 out)
  //  ws: WgT|WfT -> Q0/AO0
  const size_t MB = 1ull << 20;
  char* ob = (char*)d_out;
  u16* QA = (u16*)(ob);
  u16* QB = (u16*)(ob + 4 * MB);
  u16* QC = (u16*)(ob + 8 * MB);
  u16* QD = (u16*)(ob + 12 * MB);
  u16* WS  = (u16*)d_ws;
  u16* WfT = WS + 1024 * 1024;

  const float* hid0 = hidden;
  const float* hid1 = hidden + (size_t)2048 * 1024;

  // 1. WvT -> D[0,2M), WgT -> ws[0,2M), WfT -> ws[2,4M)
  prep3_kernel<<<dim3(16, 16, 3), 256, 0, stream>>>(W_attn, W_v_gate, W_v_ff, QD, WS, WfT);
  // 2. V (both batches) = hidden @ WvT + bv -> A / C
  gemm_hA<1><<<dim3(8, 64), 256, 0, stream>>>(hidden, QD, QA, nullptr, b_attn + 2048, nullptr);
  // 3. VgT (both, key-permuted) = gate(V) -> B / D (WvT dead)
  gemm_gate<<<dim3(8, 64), 256, 0, stream>>>(QA, WS, WfT, QB);
  // 4. WqkT -> C (V1 dead)
  transpose_bf16_kernel<<<dim3(16, 32), 256, 0, stream>>>(W_attn, QC, 3072, 0);
  // 5. Q0 -> ws (WgT/WfT dead), K0 -> A (V0 dead)
  gemm_hA<0><<<dim3(16, 32), 256, 0, stream>>>(hid0, QC, WS, QA, b_attn, layer_idx);
  // 6. attn b0: AO0 in-place over Q0 (ws)
  attn_kernel<<<512, 256, 0, stream>>>(WS, QA, QB, WS);
  // 7. Q1 -> A (K0 dead), K1 -> B (VgT0 dead)
  gemm_hA<0><<<dim3(16, 32), 256, 0, stream>>>(hid1, QC, QA, QB, b_attn, layer_idx);
  // 8. attn b1: AO1 in-place over Q1 (A)
  attn_kernel<<<512, 256, 0, stream>>>(QA, QB, QD, QA);
  // 9. proj b1: AO1@A -> out rows [2048,4096) = C+D (WqkT/VgT1 dead)
  gemm_projf<<<dim3(16, 32), 256, 0, stream>>>(QA, W_proj, (float*)d_out + (size_t)2048 * 1024, b_proj);
  // 10. proj b0: AO0@ws -> out rows [0,2048) = A+B (AO1 consumed by step 9)
  gemm_projf<<<dim3(16, 32), 256, 0, stream>>>(WS, W_proj, (float*)d_out, b_proj);
}

// Round 20
// 213.049 us; speedup vs baseline: 1.1225x; 1.0033x over previous
//
#include <hip/hip_runtime.h>
#include <hip/hip_bf16.h>
#include <cstdint>
#include <cstddef>

typedef unsigned short u16;
typedef __bf16 bf16x8 __attribute__((ext_vector_type(8)));
typedef float f32x4 __attribute__((ext_vector_type(4)));

#define LOG2E 1.44269504088896340736f

// packed f32x2 -> bf16x2 (RTNE) in ONE VALU inst; low16=lo, high16=hi
__device__ __forceinline__ uint32_t f2bf2(float lo, float hi) {
  uint32_t r;
  asm("v_cvt_pk_bf16_f32 %0, %1, %2" : "=v"(r) : "v"(lo), "v"(hi));
  return r;
}
__device__ __forceinline__ u16 f2bf(float f) { return (u16)f2bf2(f, f); }

__device__ __forceinline__ void gload16(const u16* g, u16* l) {
  __builtin_amdgcn_global_load_lds(
      (const __attribute__((address_space(1))) void*)g,
      (__attribute__((address_space(3))) void*)l, 16, 0, 0);
}

// 2D XCD-chunked block swizzle: XCD = bid%8 (round-robin dispatch). The 8
// XCDs form a BXG x (8/BXG) grid of chunks; each XCD owns a CONTIGUOUS
// rectangle of (bx,by) tiles, minimizing its A-rows + B-cols L2 footprint.
// Requires gridDim.x % BXG == 0 and gridDim.y % (8/BXG) == 0.
template <int BXG>
__device__ __forceinline__ void xcd_swizzle(int& bx, int& by) {
  const int gx = gridDim.x;
  const int bid = blockIdx.y * gx + blockIdx.x;
  const int x = bid & 7, l = bid >> 3;
  const int tx = gx / BXG;
  const int ty = gridDim.y / (8 / BXG);
  bx = (x % BXG) * tx + l % tx;
  by = (x / BXG) * ty + l / tx;
}

// ---- fp32 (1024 x ld) column-stripe -> bf16 transposed slice ----
__global__ __launch_bounds__(256) void transpose_bf16_kernel(
    const float* __restrict__ src, u16* __restrict__ dst, int ld, int c0) {
  __shared__ u16 tile[64][65];
  const int r0 = blockIdx.x * 64, cl0 = blockIdx.y * 64;
  const int tid = threadIdx.x;
#pragma unroll
  for (int i = 0; i < 16; ++i) {
    int idx = i * 256 + tid;
    int r = idx >> 6, c = idx & 63;
    tile[c][r] = f2bf(src[(size_t)(r0 + r) * ld + c0 + cl0 + c]);
  }
  __syncthreads();
#pragma unroll
  for (int i = 0; i < 16; ++i) {
    int idx = i * 256 + tid;
    int c = idx >> 6, r = idx & 63;
    dst[(size_t)(cl0 + c) * 1024 + r0 + r] = tile[c][r];
  }
}

// ---- 3 weight transposes in one launch ----
__global__ __launch_bounds__(256) void prep3_kernel(
    const float* __restrict__ Wa, const float* __restrict__ Wg,
    const float* __restrict__ Wf,
    u16* __restrict__ dv, u16* __restrict__ dg, u16* __restrict__ df) {
  __shared__ u16 tile[64][65];
  const int z = blockIdx.z;
  const float* src = (z == 0) ? Wa : (z == 1) ? Wg : Wf;
  u16* dst = (z == 0) ? dv : (z == 1) ? dg : df;
  const int ld = (z == 0) ? 3072 : 1024;
  const int c0 = (z == 0) ? 2048 : 0;
  const int r0 = blockIdx.x * 64, cl0 = blockIdx.y * 64;
  const int tid = threadIdx.x;
#pragma unroll
  for (int i = 0; i < 16; ++i) {
    int idx = i * 256 + tid;
    int r = idx >> 6, c = idx & 63;
    tile[c][r] = f2bf(src[(size_t)(r0 + r) * ld + c0 + cl0 + c]);
  }
  __syncthreads();
#pragma unroll
  for (int i = 0; i < 16; ++i) {
    int idx = i * 256 + tid;
    int c = idx >> 6, r = idx & 63;
    dst[(size_t)(cl0 + c) * 1024 + r0 + r] = tile[c][r];
  }
}

// ---- GEMM 64x128 tile, A = f32 (reg-staged + bf16 convert), Bt bf16 ----
// EPI 0: N=2048: col<1024 -> O0 (+bias, *scale*log2e); col>=1024 -> O1 (+bias)
//        BXG=2 (2MB A + 2MB B per XCD)
// EPI 1: N=1024: O0 bf16, +bias; rows GLOBAL 0..4095, batch stride 4194304 u16
//        BXG=1 (B only 2MB; 1D partition of 16MB f32 A is optimal)
template <int EPI>
__global__ __launch_bounds__(256) void gemm_hA(
    const float* __restrict__ A,
    const u16* __restrict__ Bt,
    u16* __restrict__ O0, u16* __restrict__ O1,
    const float* __restrict__ bias,
    const int* __restrict__ layer_idx) {
  __shared__ u16 lds_a[2][64 * 40];
  __shared__ u16 lds_b[2][128 * 32];
  const int tid = threadIdx.x;
  const int wid = tid >> 6, lane = tid & 63;
  const int lrow = lane & 15, lgrp = lane >> 4;
  int bxs, bys;
  xcd_swizzle<(EPI == 0) ? 2 : 1>(bxs, bys);
  const int brow = bys * 64;
  const int bcol = bxs * 128;
  const int wr = wid >> 1, wc = wid & 1;

  f32x4 acc[2][4] = {};

  const int wchunk0 = wid, wchunk1 = 4 + wid;
  const int cB0 = wchunk0 * 64 + lane, cB1 = wchunk1 * 64 + lane;
  const int rB0 = cB0 >> 2, col8B0 = (cB0 & 3) << 3;
  const int rB1 = cB1 >> 2, col8B1 = (cB1 & 3) << 3;

  // prologue
  gload16(Bt + (size_t)(bcol + rB0) * 1024 + col8B0, lds_b[0] + wchunk0 * 512);
  gload16(Bt + (size_t)(bcol + rB1) * 1024 + col8B1, lds_b[0] + wchunk1 * 512);
  {
    float4 v[2];
#pragma unroll
    for (int j = 0; j < 2; ++j) {
      int idx = j * 256 + tid;
      int m = idx >> 3, k4 = (idx & 7) << 2;
      v[j] = *(const float4*)(A + (size_t)(brow + m) * 1024 + k4);
    }
#pragma unroll
    for (int j = 0; j < 2; ++j) {
      int idx = j * 256 + tid;
      int m = idx >> 3, k4 = (idx & 7) << 2;
      uint2 w;
      w.x = f2bf2(v[j].x, v[j].y);
      w.y = f2bf2(v[j].z, v[j].w);
      *(uint2*)(lds_a[0] + m * 40 + k4) = w;
    }
  }

  for (int k0 = 0; k0 < 1024; k0 += 32) {
    const int bi = (k0 >> 5) & 1;
    __syncthreads();
    bf16x8 af[2], bfr[4];
#pragma unroll
    for (int mi = 0; mi < 2; ++mi)
      af[mi] = *(const bf16x8*)(lds_a[bi] + (wr * 32 + mi * 16 + lrow) * 40 + lgrp * 8);
#pragma unroll
    for (int nj = 0; nj < 4; ++nj)
      bfr[nj] = *(const bf16x8*)(lds_b[bi] + (wc * 64 + nj * 16 + lrow) * 32 + lgrp * 8);

    float4 v[2];
    if (k0 < 992) {
      const int kn = k0 + 32;
      gload16(Bt + (size_t)(bcol + rB0) * 1024 + kn + col8B0, lds_b[bi ^ 1] + wchunk0 * 512);
      gload16(Bt + (size_t)(bcol + rB1) * 1024 + kn + col8B1, lds_b[bi ^ 1] + wchunk1 * 512);
#pragma unroll
      for (int j = 0; j < 2; ++j) {
        int idx = j * 256 + tid;
        int m = idx >> 3, k4 = (idx & 7) << 2;
        v[j] = *(const float4*)(A + (size_t)(brow + m) * 1024 + kn + k4);
      }
    }

#pragma unroll
    for (int mi = 0; mi < 2; ++mi)
#pragma unroll
      for (int nj = 0; nj < 4; ++nj)
        acc[mi][nj] = __builtin_amdgcn_mfma_f32_16x16x32_bf16(af[mi], bfr[nj], acc[mi][nj], 0, 0, 0);

    if (k0 < 992) {
#pragma unroll
      for (int j = 0; j < 2; ++j) {
        int idx = j * 256 + tid;
        int m = idx >> 3, k4 = (idx & 7) << 2;
        uint2 w;
        w.x = f2bf2(v[j].x, v[j].y);
        w.y = f2bf2(v[j].z, v[j].w);
        *(uint2*)(lds_a[bi ^ 1] + m * 40 + k4) = w;
      }
    }
  }

  float scale = 1.0f;
  if (EPI == 0) scale = 0.125f * LOG2E / (1.0f + (float)(*layer_idx));

#pragma unroll
  for (int mi = 0; mi < 2; ++mi) {
#pragma unroll
    for (int nj = 0; nj < 4; ++nj) {
#pragma unroll
      for (int r = 0; r < 4; ++r) {
        int row = brow + wr * 32 + mi * 16 + lgrp * 4 + r;
        int col = bcol + wc * 64 + nj * 16 + lrow;
        float vv = acc[mi][nj][r] + bias[col];
        if (EPI == 0) {
          if (col < 1024) {
            O0[(size_t)row * 1024 + col] = f2bf(vv * scale);
          } else {
            O1[(size_t)row * 1024 + (col - 1024)] = f2bf(vv);
          }
        } else {
          size_t oidx = (size_t)(row >> 11) * 4194304 + (size_t)(row & 2047) * 1024 + col;
          O0[oidx] = f2bf(vv);
        }
      }
    }
  }
}

// ---- fused gate/ff GEMM, 64x128 tile, both batches (BXG=2) ----
// Writes VgT with key positions PERMUTED within each 32-key group so that
// attention's PV B-operand slot s holds key pi(s):
//   pi(s): j=s&7, g=s>>3; j<4 -> key g*4+j ; j>=4 -> key 16+g*4+(j-4)
__global__ __launch_bounds__(256) void gemm_gate(
    const u16* __restrict__ A,
    const u16* __restrict__ Bg, const u16* __restrict__ Bf,
    u16* __restrict__ VgT) {
  __shared__ u16 lds_a[2][64 * 32];
  __shared__ u16 lds_g[2][128 * 32];
  __shared__ u16 lds_f[2][128 * 32];
  const int tid = threadIdx.x;
  const int wid = tid >> 6, lane = tid & 63;
  const int lrow = lane & 15, lgrp = lane >> 4;
  int bxs, bys;
  xcd_swizzle<2>(bxs, bys);
  const int browg = bys * 64;
  const int batch = browg >> 11;
  const int brow = browg & 2047;
  const u16* Ab = A + (size_t)batch * 4194304;
  u16* VgTb = VgT + (size_t)batch * 4194304;
  const int bcol = bxs * 128;
  const int wr = wid >> 1, wc = wid & 1;

  f32x4 accg[2][4] = {};
  f32x4 accf[2][4] = {};

  const int wchunk0 = wid, wchunk1 = 4 + wid;
  const int cA = wchunk0 * 64 + lane;
  const int rA = cA >> 2, col8A = (cA & 3) << 3;
  const int cB0 = wchunk0 * 64 + lane, cB1 = wchunk1 * 64 + lane;
  const int rB0 = cB0 >> 2, col8B0 = (cB0 & 3) << 3;
  const int rB1 = cB1 >> 2, col8B1 = (cB1 & 3) << 3;

  auto stage = [&](int k0, int bi) {
    gload16(Ab + (size_t)(brow + rA) * 1024 + k0 + col8A, lds_a[bi] + wchunk0 * 512);
    gload16(Bg + (size_t)(bcol + rB0) * 1024 + k0 + col8B0, lds_g[bi] + wchunk0 * 512);
    gload16(Bg + (size_t)(bcol + rB1) * 1024 + k0 + col8B1, lds_g[bi] + wchunk1 * 512);
    gload16(Bf + (size_t)(bcol + rB0) * 1024 + k0 + col8B0, lds_f[bi] + wchunk0 * 512);
    gload16(Bf + (size_t)(bcol + rB1) * 1024 + k0 + col8B1, lds_f[bi] + wchunk1 * 512);
  };

  stage(0, 0);
  for (int k0 = 0; k0 < 1024; k0 += 32) {
    const int bi = (k0 >> 5) & 1;
    __syncthreads();
    bf16x8 af[2], bg[4], bff[4];
#pragma unroll
    for (int mi = 0; mi < 2; ++mi)
      af[mi] = *(const bf16x8*)(lds_a[bi] + (wr * 32 + mi * 16 + lrow) * 32 + lgrp * 8);
#pragma unroll
    for (int nj = 0; nj < 4; ++nj) {
      bg[nj]  = *(const bf16x8*)(lds_g[bi] + (wc * 64 + nj * 16 + lrow) * 32 + lgrp * 8);
      bff[nj] = *(const bf16x8*)(lds_f[bi] + (wc * 64 + nj * 16 + lrow) * 32 + lgrp * 8);
    }
    if (k0 < 992) stage(k0 + 32, bi ^ 1);
#pragma unroll
    for (int mi = 0; mi < 2; ++mi)
#pragma unroll
      for (int nj = 0; nj < 4; ++nj) {
        accg[mi][nj] = __builtin_amdgcn_mfma_f32_16x16x32_bf16(af[mi], bg[nj],  accg[mi][nj], 0, 0, 0);
        accf[mi][nj] = __builtin_amdgcn_mfma_f32_16x16x32_bf16(af[mi], bff[nj], accf[mi][nj], 0, 0, 0);
      }
  }

#pragma unroll
  for (int mi = 0; mi < 2; ++mi) {
#pragma unroll
    for (int nj = 0; nj < 4; ++nj) {
      int row0 = brow + wr * 32 + mi * 16 + lgrp * 4;  // key position, mult of 4
      int n = bcol + wc * 64 + nj * 16 + lrow;
      int k5 = row0 & 31;
      int s0 = (k5 < 16) ? ((k5 >> 2) * 8) : (((k5 - 16) >> 2) * 8 + 4);
      int pos = (row0 & ~31) + s0;
      uint2 w;
      w.x = f2bf2(fmaxf(accg[mi][nj][0], 0.f) * accf[mi][nj][0],
                  fmaxf(accg[mi][nj][1], 0.f) * accf[mi][nj][1]);
      w.y = f2bf2(fmaxf(accg[mi][nj][2], 0.f) * accf[mi][nj][2],
                  fmaxf(accg[mi][nj][3], 0.f) * accf[mi][nj][3]);
      *(uint2*)(VgTb + (size_t)n * 2048 + pos) = w;
    }
  }
}

// ---- projection GEMM 64x64 tile (BXG=2): A bf16, Wp f32 fused-transpose ----
__global__ __launch_bounds__(256) void gemm_projf(
    const u16* __restrict__ A,
    const float* __restrict__ Wp,
    float* __restrict__ Cout,
    const float* __restrict__ bias) {
  __shared__ u16 lds_a[2][64 * 32];
  __shared__ u16 lds_bt[2][64 * 40];
  const int tid = threadIdx.x;
  const int wid = tid >> 6, lane = tid & 63;
  const int lrow = lane & 15, lgrp = lane >> 4;
  int bxs, bys;
  xcd_swizzle<2>(bxs, bys);
  const int brow = bys * 64;
  const int bcol = bxs * 64;
  const int wr = wid >> 1, wc = wid & 1;

  f32x4 acc[2][2] = {};

  const int cA = wid * 64 + lane;
  const int rA = cA >> 2, col8A = (cA & 3) << 3;
  const int ng = tid & 15, kp = tid >> 4;
  const int n4 = ng << 2, kk = kp << 1;
  const int kc = kk >> 3, klo = kk & 7;

  auto stageB = [&](int k0, int bi) {
    float4 va = *(const float4*)(Wp + (size_t)(k0 + kk) * 1024 + bcol + n4);
    float4 vb = *(const float4*)(Wp + (size_t)(k0 + kk + 1) * 1024 + bcol + n4);
    const float a4[4] = {va.x, va.y, va.z, va.w};
    const float b4[4] = {vb.x, vb.y, vb.z, vb.w};
#pragma unroll
    for (int i = 0; i < 4; ++i) {
      int row = n4 + i;
      int sw = (kc ^ ((row >> 2) & 3)) << 3;
      u16* p = lds_bt[bi] + row * 40 + sw + klo;
      *(uint32_t*)p = f2bf2(a4[i], b4[i]);
    }
  };

  // prologue
  gload16(A + (size_t)(brow + rA) * 1024 + col8A, lds_a[0] + wid * 512);
  stageB(0, 0);

  for (int k0 = 0; k0 < 1024; k0 += 32) {
    const int bi = (k0 >> 5) & 1;
    __syncthreads();
    bf16x8 af[2], bfr[2];
#pragma unroll
    for (int mi = 0; mi < 2; ++mi)
      af[mi] = *(const bf16x8*)(lds_a[bi] + (wr * 32 + mi * 16 + lrow) * 32 + lgrp * 8);
#pragma unroll
    for (int nj = 0; nj < 2; ++nj) {
      int rowb = wc * 32 + nj * 16 + lrow;
      bfr[nj] = *(const bf16x8*)(lds_bt[bi] + rowb * 40 + ((lgrp ^ ((rowb >> 2) & 3)) << 3));
    }

    if (k0 < 992) {
      const int kn = k0 + 32;
      gload16(A + (size_t)(brow + rA) * 1024 + kn + col8A, lds_a[bi ^ 1] + wid * 512);
      stageB(kn, bi ^ 1);
    }

#pragma unroll
    for (int mi = 0; mi < 2; ++mi)
#pragma unroll
      for (int nj = 0; nj < 2; ++nj)
        acc[mi][nj] = __builtin_amdgcn_mfma_f32_16x16x32_bf16(af[mi], bfr[nj], acc[mi][nj], 0, 0, 0);
  }

#pragma unroll
  for (int mi = 0; mi < 2; ++mi)
#pragma unroll
    for (int nj = 0; nj < 2; ++nj)
#pragma unroll
      for (int r = 0; r < 4; ++r) {
        int row = brow + wr * 32 + mi * 16 + lgrp * 4 + r;
        int col = bcol + wc * 32 + nj * 16 + lrow;
        Cout[(size_t)row * 1024 + col] = acc[mi][nj][r] + bias[col];
      }
}

// ---- flash attention: KEY-SPLIT waves + SWAPPED QK^T, in-register P ----
// (unchanged from R19 best: 64 q-rows x 128-key tiles, wave w owns keys
// w*32..w*32+31, P in-register via mfma(K,Q) + VgT key permutation, dbuf
// LDS 1 barrier/tile, no-max softmax with log2e folded into Q scale.)
__global__ __launch_bounds__(256) void attn_kernel(
    const u16* Qb, const u16* __restrict__ Kb,
    const u16* __restrict__ VgTb, u16* AO) {
  __shared__ u16 lds_kv[2][16384];   // per buf: K[128*64] | V[64*128] (32KB)
  __shared__ float lds_ls[4][64];    // per-wave lsum partials
  const int tid = threadIdx.x, wid = tid >> 6, lane = tid & 63;
  const int lrow = lane & 15, lgrp = lane >> 4;
  const int f = blockIdx.x;
  const int h = f & 15;
  const int idx = f >> 4;
  const int qt = (idx < 16) ? idx : 47 - idx;  // f and f+256 sum to 31
  const int nt = (qt >> 1) + 1;

  bf16x8 qf[4][2];
#pragma unroll
  for (int qg = 0; qg < 4; ++qg) {
    const u16* qp = Qb + (size_t)(qt * 64 + qg * 16 + lrow) * 1024 + h * 64 + lgrp * 8;
    qf[qg][0] = *(const bf16x8*)(qp);
    qf[qg][1] = *(const bf16x8*)(qp + 32);
  }

  int krow[4], kch[4], vrow[4], vch[4];
#pragma unroll
  for (int i = 0; i < 4; ++i) {
    int c = i * 256 + tid;
    krow[i] = c >> 3; kch[i] = c & 7;
    vrow[i] = c >> 4; vch[i] = c & 15;
  }
  bf16x8 kreg[4], vreg[4];

  auto stage_load = [&](int t) {
#pragma unroll
    for (int i = 0; i < 4; ++i) {
      kreg[i] = *(const bf16x8*)(Kb + (size_t)(t * 128 + krow[i]) * 1024 + h * 64 + kch[i] * 8);
      vreg[i] = *(const bf16x8*)(VgTb + (size_t)(h * 64 + vrow[i]) * 2048 + t * 128 + vch[i] * 8);
    }
  };
  auto stage_write = [&](int bi) {
#pragma unroll
    for (int i = 0; i < 4; ++i) {
      *(bf16x8*)(lds_kv[bi] + krow[i] * 64 + ((kch[i] ^ (krow[i] & 7)) << 3)) = kreg[i];
      *(bf16x8*)(lds_kv[bi] + 8192 + vrow[i] * 128 + ((vch[i] ^ (vrow[i] & 7)) << 3)) = vreg[i];
    }
  };

  stage_load(0);
  stage_write(0);
  __syncthreads();

  f32x4 oacc[4][4] = {};
  float lsum[4] = {0.f, 0.f, 0.f, 0.f};

  for (int t = 0; t < nt; ++t) {
    const int bi = t & 1;
    if (t + 1 < nt) stage_load(t + 1);
    const u16* lk = lds_kv[bi];
    const u16* lv = lds_kv[bi] + 8192;

    bf16x8 kf[2][2];
#pragma unroll
    for (int ks = 0; ks < 2; ++ks)
#pragma unroll
      for (int nj2 = 0; nj2 < 2; ++nj2) {
        int row = wid * 32 + nj2 * 16 + lrow;
        kf[ks][nj2] = *(const bf16x8*)(lk + row * 64 + (((ks * 4 + lgrp) ^ (lrow & 7)) << 3));
      }
    bf16x8 vf[4];
#pragma unroll
    for (int dt = 0; dt < 4; ++dt)
      vf[dt] = *(const bf16x8*)(lv + (dt * 16 + lrow) * 128 + (((wid * 4 + lgrp) ^ (lrow & 7)) << 3));

    f32x4 sacc[4][2] = {};
#pragma unroll
    for (int qg = 0; qg < 4; ++qg)
#pragma unroll
      for (int ks = 0; ks < 2; ++ks)
#pragma unroll
        for (int nj2 = 0; nj2 < 2; ++nj2)
          sacc[qg][nj2] = __builtin_amdgcn_mfma_f32_16x16x32_bf16(kf[ks][nj2], qf[qg][ks], sacc[qg][nj2], 0, 0, 0);

    const bool last = (t == nt - 1);
#pragma unroll
    for (int qg = 0; qg < 4; ++qg) {
#pragma unroll
      for (int nj2 = 0; nj2 < 2; ++nj2) {
#pragma unroll
        for (int r = 0; r < 4; ++r) {
          float p;
          if (last) {
            int key = t * 128 + wid * 32 + nj2 * 16 + lgrp * 4 + r;
            int srow = qt * 64 + qg * 16 + lrow;
            p = (key > srow) ? 0.f : exp2f(sacc[qg][nj2][r]);
          } else {
            p = exp2f(sacc[qg][nj2][r]);
          }
          sacc[qg][nj2][r] = p;
          lsum[qg] += p;
        }
      }
    }

#pragma unroll
    for (int qg = 0; qg < 4; ++qg) {
      union { uint32_t u[4]; bf16x8 v; } pa;
      pa.u[0] = f2bf2(sacc[qg][0][0], sacc[qg][0][1]);
      pa.u[1] = f2bf2(sacc[qg][0][2], sacc[qg][0][3]);
      pa.u[2] = f2bf2(sacc[qg][1][0], sacc[qg][1][1]);
      pa.u[3] = f2bf2(sacc[qg][1][2], sacc[qg][1][3]);
#pragma unroll
      for (int dt = 0; dt < 4; ++dt)
        oacc[qg][dt] = __builtin_amdgcn_mfma_f32_16x16x32_bf16(pa.v, vf[dt], oacc[qg][dt], 0, 0, 0);
    }

    if (t + 1 < nt) stage_write(bi ^ 1);
    __syncthreads();
  }

#pragma unroll
  for (int qg = 0; qg < 4; ++qg) {
    lsum[qg] += __shfl_xor(lsum[qg], 16);
    lsum[qg] += __shfl_xor(lsum[qg], 32);
  }
  if (lgrp == 0) {
#pragma unroll
    for (int qg = 0; qg < 4; ++qg) lds_ls[wid][qg * 16 + lrow] = lsum[qg];
  }

  float* red = (float*)lds_kv;
#pragma unroll
  for (int qg = 0; qg < 4; ++qg)
#pragma unroll
    for (int dt = 0; dt < 4; ++dt)
      *(f32x4*)(red + dt * 4096 + qg * 1024 + wid * 256 + lane * 4) = oacc[qg][dt];
  __syncthreads();

#pragma unroll
  for (int qg = 0; qg < 4; ++qg) {
    f32x4 s = *(const f32x4*)(red + wid * 4096 + qg * 1024 + 0 * 256 + lane * 4);
#pragma unroll
    for (int w = 1; w < 4; ++w) {
      f32x4 x = *(const f32x4*)(red + wid * 4096 + qg * 1024 + w * 256 + lane * 4);
      s[0] += x[0]; s[1] += x[1]; s[2] += x[2]; s[3] += x[3];
    }
#pragma unroll
    for (int r = 0; r < 4; ++r) {
      int q = qg * 16 + lgrp * 4 + r;
      float ls = lds_ls[0][q] + lds_ls[1][q] + lds_ls[2][q] + lds_ls[3][q];
      AO[(size_t)(qt * 64 + q) * 1024 + h * 64 + wid * 16 + lrow] = f2bf(s[r] / ls);
    }
  }
}

extern "C" void kernel_launch(void* const* d_in, const int* in_sizes, int n_in,
                              void* d_out, int out_size, void* d_ws, size_t ws_size,
                              hipStream_t stream) {
  const float* hidden    = (const float*)d_in[0];
  // d_in[1] = mask (causal tril by construction; not read)
  const int*   layer_idx = (const int*)d_in[2];
  const float* W_attn    = (const float*)d_in[3];
  const float* b_attn    = (const float*)d_in[4];
  const float* W_proj    = (const float*)d_in[5];
  const float* b_proj    = (const float*)d_in[6];
  const float* W_v_ff    = (const float*)d_in[7];
  const float* W_v_gate  = (const float*)d_in[8];

  // ws peak: 4 MiB. d_out quarters (4MB each) carry intermediates:
  //  A: V0 -> K0 -> Q1/AO1 -> (f32 out)     B: VgT0 -> K1 -> (f32 out)
  //  C: V1 -> WqkT -> (f32 out)             D: WvT -> VgT1 -> (f32 out)
  //  ws: WgT|WfT -> Q0/AO0
  const size_t MB = 1ull << 20;
  char* ob = (char*)d_out;
  u16* QA = (u16*)(ob);
  u16* QB = (u16*)(ob + 4 * MB);
  u16* QC = (u16*)(ob + 8 * MB);
  u16* QD = (u16*)(ob + 12 * MB);
  u16* WS  = (u16*)d_ws;
  u16* WfT = WS + 1024 * 1024;

  const float* hid0 = hidden;
  const float* hid1 = hidden + (size_t)2048 * 1024;

  // 1. WvT -> D[0,2M), WgT -> ws[0,2M), WfT -> ws[2,4M)
  prep3_kernel<<<dim3(16, 16, 3), 256, 0, stream>>>(W_attn, W_v_gate, W_v_ff, QD, WS, WfT);
  // 2. V (both batches) = hidden @ WvT + bv -> A / C
  gemm_hA<1><<<dim3(8, 64), 256, 0, stream>>>(hidden, QD, QA, nullptr, b_attn + 2048, nullptr);
  // 3. VgT (both, key-permuted) = gate(V) -> B / D (WvT dead)
  gemm_gate<<<dim3(8, 64), 256, 0, stream>>>(QA, WS, WfT, QB);
  // 4. WqkT -> C (V1 dead)
  transpose_bf16_kernel<<<dim3(16, 32), 256, 0, stream>>>(W_attn, QC, 3072, 0);
  // 5. Q0 -> ws (WgT/WfT dead), K0 -> A (V0 dead)
  gemm_hA<0><<<dim3(16, 32), 256, 0, stream>>>(hid0, QC, WS, QA, b_attn, layer_idx);
  // 6. attn b0: AO0 in-place over Q0 (ws)
  attn_kernel<<<512, 256, 0, stream>>>(WS, QA, QB, WS);
  // 7. Q1 -> A (K0 dead), K1 -> B (VgT0 dead)
  gemm_hA<0><<<dim3(16, 32), 256, 0, stream>>>(hid1, QC, QA, QB, b_attn, layer_idx);
  // 8. attn b1: AO1 in-place over Q1 (A)
  attn_kernel<<<512, 256, 0, stream>>>(QA, QB, QD, QA);
  // 9. proj b1: AO1@A -> out rows [2048,4096) = C+D (WqkT/VgT1 dead)
  gemm_projf<<<dim3(16, 32), 256, 0, stream>>>(QA, W_proj, (float*)d_out + (size_t)2048 * 1024, b_proj);
  // 10. proj b0: AO0@ws -> out rows [0,2048) = A+B (AO1 consumed by step 9)
  gemm_projf<<<dim3(16, 32), 256, 0, stream>>>(WS, W_proj, (float*)d_out, b_proj);
}